// Round 4
// baseline (234.833 us; speedup 1.0000x reference)
//
#include <hip/hip_runtime.h>
#include <math.h>

#define S_LEN 2048
#define D_KV  64
#define BQ    128   // q rows per block: 4 waves x 32
#define BK    64
#define NT    (S_LEN / BK)   // 32 k-tiles

typedef __attribute__((ext_vector_type(8)))  short bh8;   // 8 bf16 (MFMA A/B frag)
typedef __attribute__((ext_vector_type(4)))  float fx4;
typedef __attribute__((ext_vector_type(16))) float fx16;  // 32x32 MFMA C/D frag
typedef __attribute__((ext_vector_type(4)))  unsigned int u32x4;
typedef __attribute__((ext_vector_type(2)))  unsigned int u32x2;

__device__ __forceinline__ unsigned cvt2(float a, float b) {
    unsigned r;
    asm("v_cvt_pk_bf16_f32 %0, %1, %2" : "=v"(r) : "v"(a), "v"(b));
    return r;
}
// v_permlane32_swap_b32 d, s: exchanges d lanes 32-63 with s lanes 0-31.
// (d' = {d.lo, s.lo}, s' = {d.hi, s.hi} viewed lane-wise across the halves.)
__device__ __forceinline__ void swap32(unsigned &d, unsigned &s) {
    asm("v_permlane32_swap_b32 %0, %1" : "+v"(d), "+v"(s));
}
// row-major [row][64 bf16] tile, canonical bank swizzle (conflict-free for
// 32x32 A-frag reads: consecutive lanes = consecutive rows -> distinct slots)
__device__ __forceinline__ int swz(int row, int byteoff) {
    return (row << 7) + (byteoff ^ ((row & 7) << 4));
}

__global__ __launch_bounds__(256, 3)
void attn_fwd(const float* __restrict__ Qg, const float* __restrict__ Kg,
              const float* __restrict__ Vg, const float* __restrict__ Mg,
              float* __restrict__ Og)
{
    __shared__ __align__(16) char smem[16384];
    short* kb = (short*)smem;           // K  [64 keys][64 d] bf16, swizzled
    short* vb = (short*)(smem + 8192);  // V^T[64 d][64 keys] bf16, swizzled

    const int tid  = threadIdx.x;
    const int lane = tid & 63;
    const int wave = tid >> 6;    // 0..3
    const int lq   = lane & 31;   // q row within wave tile (MFMA col)
    const int hf   = lane >> 5;   // half-wave (k-slice selector)

    // XCD-aware bijective swizzle: 512 blocks, 64 contiguous per XCD
    const int flat = blockIdx.x + (int)gridDim.x * blockIdx.y;   // 0..511
    const int nsw  = (flat & 7) * 64 + (flat >> 3);
    const int qt = nsw & 15;
    const int bh = nsw >> 4;
    const int b  = bh >> 4;

    const int qbase = qt * BQ + wave * 32;

    const float* Kp = Kg + (size_t)bh * S_LEN * D_KV;
    const float* Vp = Vg + (size_t)bh * S_LEN * D_KV;
    const float* Qp = Qg + ((size_t)bh * S_LEN + qbase) * D_KV;
    const float* mrow = Mg + (size_t)b * S_LEN * S_LEN
                      + (size_t)(qbase + lq) * S_LEN + hf * 4;

    // ---- Q as 32x32x16 B-frags (col = q = lq, k = hf*8+j), scale 1/8 ----
    bh8 qf[4];
#pragma unroll
    for (int ks = 0; ks < 4; ++ks) {
        const float* src = Qp + lq * D_KV + ks * 16 + hf * 8;
        fx4 a0 = *(const fx4*)src;
        fx4 a1 = *(const fx4*)(src + 4);
        u32x4 q4 = { cvt2(a0[0] * 0.125f, a0[1] * 0.125f),
                     cvt2(a0[2] * 0.125f, a0[3] * 0.125f),
                     cvt2(a1[0] * 0.125f, a1[1] * 0.125f),
                     cvt2(a1[2] * 0.125f, a1[3] * 0.125f) };
        qf[ks] = __builtin_bit_cast(bh8, q4);
    }

    // ---- staging maps (all 256 threads stage both K and V) ----
    const int krow = tid >> 2;           // K: one row per 4 threads
    const int kcol = (tid & 3) << 2;     // float col base; +16 per i
    const int vd0  = (tid >> 4) << 2;    // V: 4x4 transpose block
    const int vk0  = (tid & 15) << 2;

    fx16 o0 = {}, o1 = {};               // O^T[d][q=lq], d-blocks 0/1
    float lsum = 0.f;
    fx4 kreg[4], vreg[4];                // T14 prefetch registers

    // prologue: prefetch tile 0
#pragma unroll
    for (int i = 0; i < 4; ++i)
        kreg[i] = *(const fx4*)(Kp + (size_t)krow * D_KV + kcol + 16 * i);
#pragma unroll
    for (int i = 0; i < 4; ++i)
        vreg[i] = *(const fx4*)(Vp + (size_t)(vk0 + i) * D_KV + vd0);

#pragma unroll 1
    for (int t = 0; t < NT; ++t) {
        const int kt = t * BK;

        // ---- issue rb=0 mask loads (independent of LDS; in flight early) ----
        fx4 mv0[4];
#pragma unroll
        for (int m = 0; m < 4; ++m)
            mv0[m] = *(const fx4*)(mrow + kt + m * 8);

        // ---- drain prefetched K/V regs -> swizzled LDS ----
#pragma unroll
        for (int i = 0; i < 4; ++i) {
            u32x2 w = { cvt2(kreg[i][0], kreg[i][1]),
                        cvt2(kreg[i][2], kreg[i][3]) };
            *(u32x2*)((char*)kb + swz(krow, (kcol << 1) + 32 * i)) = w;
        }
#pragma unroll
        for (int i = 0; i < 4; ++i) {
            u32x2 w = { cvt2(vreg[0][i], vreg[1][i]),
                        cvt2(vreg[2][i], vreg[3][i]) };
            *(u32x2*)((char*)vb + swz(vd0 + i, vk0 << 1)) = w;
        }
        __syncthreads();

        // ---- prefetch next tile while computing this one ----
        if (t + 1 < NT) {
            const int kn = kt + BK;
#pragma unroll
            for (int i = 0; i < 4; ++i)
                kreg[i] = *(const fx4*)(Kp + (size_t)(kn + krow) * D_KV + kcol + 16 * i);
#pragma unroll
            for (int i = 0; i < 4; ++i)
                vreg[i] = *(const fx4*)(Vp + (size_t)(kn + vk0 + i) * D_KV + vd0);
        }

        // ---- QK^T swapped: st = mfma(K, Q) = S^T[key][q=lq] ----
        // key(reg r, rb) = rb*32 + 8*(r>>2) + 4*hf + (r&3)
        fx16 st0 = {}, st1 = {};
        __builtin_amdgcn_s_setprio(1);
#pragma unroll
        for (int ks = 0; ks < 4; ++ks) {
            bh8 k0 = *(const bh8*)((char*)kb + swz(lq,      ks * 32 + hf * 16));
            bh8 k1 = *(const bh8*)((char*)kb + swz(32 + lq, ks * 32 + hf * 16));
            st0 = __builtin_amdgcn_mfma_f32_32x32x16_bf16(k0, qf[ks], st0, 0, 0, 0);
            st1 = __builtin_amdgcn_mfma_f32_32x32x16_bf16(k1, qf[ks], st1, 0, 0, 0);
        }
        __builtin_amdgcn_s_setprio(0);

        // ---- issue rb=1 mask loads under softmax rb=0 ----
        fx4 mv1[4];
#pragma unroll
        for (int m = 0; m < 4; ++m)
            mv1[m] = *(const fx4*)(mrow + kt + 32 + m * 8);

        unsigned pkw[16];

        // ---- softmax rb=0: mask * keep-positive * exp (fixed max 0) ----
#pragma unroll
        for (int m = 0; m < 4; ++m) {
            float tm0 = st0[4*m+0] * mv0[m][0];
            float tm1 = st0[4*m+1] * mv0[m][1];
            float tm2 = st0[4*m+2] * mv0[m][2];
            float tm3 = st0[4*m+3] * mv0[m][3];
            float p0 = tm0 > 0.f ? __expf(tm0) : 0.f;
            float p1 = tm1 > 0.f ? __expf(tm1) : 0.f;
            float p2 = tm2 > 0.f ? __expf(tm2) : 0.f;
            float p3 = tm3 > 0.f ? __expf(tm3) : 0.f;
            lsum += (p0 + p1) + (p2 + p3);
            pkw[m*2+0] = cvt2(p0, p1);
            pkw[m*2+1] = cvt2(p2, p3);
        }

        // ---- PV keys 0..31: B-frag assembled via permlane32_swap (T12) ----
        // swap32(w0,w2): w0.hi <-> w2.lo  =>  after both swaps, frag words
        // {w0,w1,w2,w3} give hf=0 keys [0..7]+16vp, hf=1 keys [8..15]+16vp.
        __builtin_amdgcn_s_setprio(1);
#pragma unroll
        for (int vp = 0; vp < 2; ++vp) {
            unsigned w0 = pkw[vp*4+0], w1 = pkw[vp*4+1];
            unsigned w2 = pkw[vp*4+2], w3 = pkw[vp*4+3];
            swap32(w0, w2); swap32(w1, w3);
            u32x4 pq = { w0, w1, w2, w3 };
            bh8 pb = __builtin_bit_cast(bh8, pq);
            bh8 v0 = *(const bh8*)((char*)vb + swz(lq,      vp * 32 + hf * 16));
            bh8 v1 = *(const bh8*)((char*)vb + swz(32 + lq, vp * 32 + hf * 16));
            o0 = __builtin_amdgcn_mfma_f32_32x32x16_bf16(v0, pb, o0, 0, 0, 0);
            o1 = __builtin_amdgcn_mfma_f32_32x32x16_bf16(v1, pb, o1, 0, 0, 0);
        }
        __builtin_amdgcn_s_setprio(0);

        // ---- softmax rb=1 ----
#pragma unroll
        for (int m = 0; m < 4; ++m) {
            float tm0 = st1[4*m+0] * mv1[m][0];
            float tm1 = st1[4*m+1] * mv1[m][1];
            float tm2 = st1[4*m+2] * mv1[m][2];
            float tm3 = st1[4*m+3] * mv1[m][3];
            float p0 = tm0 > 0.f ? __expf(tm0) : 0.f;
            float p1 = tm1 > 0.f ? __expf(tm1) : 0.f;
            float p2 = tm2 > 0.f ? __expf(tm2) : 0.f;
            float p3 = tm3 > 0.f ? __expf(tm3) : 0.f;
            lsum += (p0 + p1) + (p2 + p3);
            pkw[8 + m*2+0] = cvt2(p0, p1);
            pkw[8 + m*2+1] = cvt2(p2, p3);
        }

        // ---- PV keys 32..63 ----
        __builtin_amdgcn_s_setprio(1);
#pragma unroll
        for (int vp = 2; vp < 4; ++vp) {
            unsigned w0 = pkw[vp*4+0], w1 = pkw[vp*4+1];
            unsigned w2 = pkw[vp*4+2], w3 = pkw[vp*4+3];
            swap32(w0, w2); swap32(w1, w3);
            u32x4 pq = { w0, w1, w2, w3 };
            bh8 pb = __builtin_bit_cast(bh8, pq);
            bh8 v0 = *(const bh8*)((char*)vb + swz(lq,      vp * 32 + hf * 16));
            bh8 v1 = *(const bh8*)((char*)vb + swz(32 + lq, vp * 32 + hf * 16));
            o0 = __builtin_amdgcn_mfma_f32_32x32x16_bf16(v0, pb, o0, 0, 0, 0);
            o1 = __builtin_amdgcn_mfma_f32_32x32x16_bf16(v1, pb, o1, 0, 0, 0);
        }
        __builtin_amdgcn_s_setprio(0);

        __syncthreads();   // readers done before next tile's LDS writes
    }

    // ---- row sum: lane l and l^32 hold the same q, complementary keys ----
    lsum += __shfl_xor(lsum, 32);
    const float inv = 1.0f / lsum;

    // ---- epilogue: O[q][d], d = db*32 + 8m + 4*hf + j ----
    float* orow = Og + ((size_t)bh * S_LEN + qbase + lq) * D_KV;
#pragma unroll
    for (int m = 0; m < 4; ++m) {
        fx4 r0 = { o0[4*m+0]*inv, o0[4*m+1]*inv, o0[4*m+2]*inv, o0[4*m+3]*inv };
        *(fx4*)(orow + m * 8 + hf * 4) = r0;
        fx4 r1 = { o1[4*m+0]*inv, o1[4*m+1]*inv, o1[4*m+2]*inv, o1[4*m+3]*inv };
        *(fx4*)(orow + 32 + m * 8 + hf * 4) = r1;
    }
}

extern "C" void kernel_launch(void* const* d_in, const int* in_sizes, int n_in,
                              void* d_out, int out_size, void* d_ws, size_t ws_size,
                              hipStream_t stream) {
    const float* Q = (const float*)d_in[0];
    const float* K = (const float*)d_in[1];
    const float* V = (const float*)d_in[2];
    const float* M = (const float*)d_in[3];
    float*       O = (float*)d_out;
    dim3 grid(S_LEN / BQ, 32);   // 16 q-tiles x (B*H)=32
    attn_fwd<<<grid, 256, 0, stream>>>(Q, K, V, M, O);
}